// Round 1
// baseline (2530.351 us; speedup 1.0000x reference)
//
#include <hip/hip_runtime.h>
#include <math.h>

#define BB 512
#define SS 128
#define EE 300
#define HH 300
#define FCIN 1800
#define LLI 2

__device__ __forceinline__ float fast_tanh(float x){
    float ax = fabsf(x);
    float t = __expf(-2.f*ax);
    float r = (1.f - t) / (1.f + t);
    return copysignf(r, x);
}

// ---------------- embedding gather + valid mask ----------------
// grid: (bc*S/4, 2), block 256 (4 waves, one row per wave)
__global__ void embed_kernel(const int* __restrict__ seq1, const int* __restrict__ seq2,
                             const float* __restrict__ emb,
                             float* __restrict__ s1, float* __restrict__ s2,
                             float* __restrict__ v1, float* __restrict__ v2, int b0){
    int which = blockIdx.y;
    const int* seq = which ? seq2 : seq1;
    float* sd = which ? s2 : s1;
    float* vd = which ? v2 : v1;
    int wave = threadIdx.x >> 6;
    int lane = threadIdx.x & 63;
    int row = blockIdx.x*4 + wave;          // local (b,s) row index
    int bl = row / SS, sidx = row - bl*SS;
    int token = seq[(size_t)(b0+bl)*SS + sidx];
    const float* er = emb + (size_t)token * EE;
    float* out = sd + (size_t)row * EE;
    for (int e = lane; e < EE; e += 64) out[e] = er[e];
    if (lane == 0) vd[row] = (token != 0) ? 1.f : 0.f;
}

// ---------------- masked squared norms ----------------
// grid: (bc*S/4, 2), block 256
__global__ void norm_kernel(const float* __restrict__ x1, const float* __restrict__ x2,
                            const float* __restrict__ v1, const float* __restrict__ v2,
                            float* __restrict__ n1, float* __restrict__ n2){
    int which = blockIdx.y;
    const float* x = which ? x2 : x1;
    const float* v = which ? v2 : v1;
    float* n = which ? n2 : n1;
    int wave = threadIdx.x >> 6, lane = threadIdx.x & 63;
    int row = blockIdx.x*4 + wave;
    const float* xr = x + (size_t)row*EE;
    float acc = 0.f;
    for (int e = lane; e < EE; e += 64){ float t = xr[e]; acc += t*t; }
    #pragma unroll
    for (int o = 32; o > 0; o >>= 1) acc += __shfl_down(acc, o);
    if (lane == 0) n[row] = acc * v[row];
}

// ---------------- match score: full 128x128 per block ----------------
// MODE 0: write A.  MODE 1: fused w1 (row sums) / w2 (col sums), no A write.
// grid: bc blocks, block 256 (16x16 threads, 8x8 micro-tile)
#define KK 10
template<int MODE>
__global__ __launch_bounds__(256) void cross_kernel(
    const float* __restrict__ xa, const float* __restrict__ xb,
    const float* __restrict__ va, const float* __restrict__ vb,
    const float* __restrict__ na, const float* __restrict__ nb,
    float* __restrict__ Aout, float* __restrict__ w1, float* __restrict__ w2)
{
    __shared__ float As[KK][132];
    __shared__ float Bs[KK][132];
    int bl = blockIdx.x;
    const float* xar = xa + (size_t)bl*SS*EE;
    const float* xbr = xb + (size_t)bl*SS*EE;
    int tid = threadIdx.x;
    int tx = tid & 15, ty = tid >> 4;
    int i0 = ty*8, j0 = tx*8;
    float acc[8][8] = {};
    for (int k0 = 0; k0 < EE; k0 += KK){
        #pragma unroll
        for (int u = 0; u < 5; u++){
            int idx = tid + u*256;           // 0..1279
            int i = idx / KK, k = idx - i*KK;
            As[k][i] = xar[i*EE + k0 + k] * va[bl*SS + i];
            Bs[k][i] = xbr[i*EE + k0 + k] * vb[bl*SS + i];
        }
        __syncthreads();
        #pragma unroll
        for (int k = 0; k < KK; k++){
            float a[8], b[8];
            #pragma unroll
            for (int r = 0; r < 8; r++) a[r] = As[k][i0+r];
            #pragma unroll
            for (int c = 0; c < 8; c++) b[c] = Bs[k][j0+c];
            #pragma unroll
            for (int r = 0; r < 8; r++)
                #pragma unroll
                for (int c = 0; c < 8; c++)
                    acc[r][c] = fmaf(a[r], b[c], acc[r][c]);
        }
        __syncthreads();
    }
    float nr[8], nc[8];
    #pragma unroll
    for (int r = 0; r < 8; r++) nr[r] = na[bl*SS + i0+r];
    #pragma unroll
    for (int c = 0; c < 8; c++) nc[c] = nb[bl*SS + j0+c];

    float aval[8][8];
    #pragma unroll
    for (int r = 0; r < 8; r++)
        #pragma unroll
        for (int c = 0; c < 8; c++){
            float d2 = nr[r] + nc[c] - 2.f*acc[r][c];
            float d = sqrtf(fmaxf(d2, 0.f));
            aval[r][c] = 1.f / (1.f + d);
        }

    if constexpr (MODE == 0){
        float* Ar = Aout + (size_t)bl*SS*SS;
        #pragma unroll
        for (int r = 0; r < 8; r++)
            #pragma unroll
            for (int c = 0; c < 8; c++)
                Ar[(i0+r)*SS + j0+c] = aval[r][c];
    } else {
        // row sums (over j) -> w1 ; col sums (over i) -> w2
        float rowp[8], colp[8];
        #pragma unroll
        for (int r = 0; r < 8; r++){
            float s = 0.f;
            #pragma unroll
            for (int c = 0; c < 8; c++) s += aval[r][c];
            rowp[r] = s;
        }
        #pragma unroll
        for (int c = 0; c < 8; c++){
            float s = 0.f;
            #pragma unroll
            for (int r = 0; r < 8; r++) s += aval[r][c];
            colp[c] = s;
        }
        #pragma unroll
        for (int m = 1; m < 16; m <<= 1)
            #pragma unroll
            for (int r = 0; r < 8; r++) rowp[r] += __shfl_xor(rowp[r], m);
        if (tx == 0){
            #pragma unroll
            for (int r = 0; r < 8; r++) w1[bl*SS + i0+r] = rowp[r];
        }
        __shared__ float colred[16][132];
        #pragma unroll
        for (int c = 0; c < 8; c++) colred[ty][j0+c] = colp[c];
        __syncthreads();
        if (tid < SS){
            float s = 0.f;
            #pragma unroll
            for (int g = 0; g < 16; g++) s += colred[g][tid];
            w2[bl*SS + tid] = s;
        }
    }
}

// ---------------- f1 = A @ W, f2 = A^T @ W ----------------
// grid: (bc, 10, 2)  y = mtile*5 + etile, z = which; block 256, 64x64 tile, 4x4 micro
#define FKK 16
__global__ __launch_bounds__(256) void f_kernel(const float* __restrict__ Abuf,
                                                const float* __restrict__ Wl,
                                                float* __restrict__ f1, float* __restrict__ f2){
    __shared__ float At[FKK][68];
    __shared__ float Wt[FKK][68];
    int bl = blockIdx.x;
    int m = blockIdx.y / 5, et = blockIdx.y - m*5;
    int which = blockIdx.z;
    const float* Ab = Abuf + (size_t)bl*SS*SS;
    int i0g = m*64, e0g = et*64;
    int tid = threadIdx.x, tx = tid & 15, ty = tid >> 4;
    float acc[4][4] = {};
    for (int k0 = 0; k0 < SS; k0 += FKK){
        if (which == 0){
            int i = tid >> 2;
            int kb = (tid & 3) * 4;
            #pragma unroll
            for (int u = 0; u < 4; u++){
                int k = kb + u;
                At[k][i] = Ab[(i0g+i)*SS + k0 + k];
            }
        } else {
            int i = tid & 63; int kb = tid >> 6;
            #pragma unroll
            for (int u = 0; u < 4; u++){
                int k = kb + u*4;
                At[k][i] = Ab[(k0+k)*SS + i0g + i];
            }
        }
        {
            int e = tid & 63; int kb = tid >> 6;
            int ge = e0g + e;
            #pragma unroll
            for (int u = 0; u < 4; u++){
                int k = kb + u*4;
                Wt[k][e] = (ge < EE) ? Wl[(k0+k)*EE + ge] : 0.f;
            }
        }
        __syncthreads();
        #pragma unroll
        for (int k = 0; k < FKK; k++){
            float av[4], wv[4];
            #pragma unroll
            for (int r = 0; r < 4; r++) av[r] = At[k][ty*4+r];
            #pragma unroll
            for (int c = 0; c < 4; c++) wv[c] = Wt[k][tx*4+c];
            #pragma unroll
            for (int r = 0; r < 4; r++)
                #pragma unroll
                for (int c = 0; c < 4; c++)
                    acc[r][c] = fmaf(av[r], wv[c], acc[r][c]);
        }
        __syncthreads();
    }
    float* fd = which ? f2 : f1;
    #pragma unroll
    for (int r = 0; r < 4; r++){
        int gi = i0g + ty*4 + r;
        #pragma unroll
        for (int c = 0; c < 4; c++){
            int ge = e0g + tx*4 + c;
            if (ge < EE) fd[(size_t)bl*SS*EE + gi*EE + ge] = acc[r][c];
        }
    }
}

// ---------------- conv(3x3, 2ch) + tanh ----------------
// grid: (bc, 8, 2), block 256; 16 output rows per block, LDS staged with halo
__global__ __launch_bounds__(256) void conv_kernel(const float* __restrict__ s1, const float* __restrict__ s2,
                                                   const float* __restrict__ f1, const float* __restrict__ f2,
                                                   const float* __restrict__ cw, const float* __restrict__ cb,
                                                   float* __restrict__ o1, float* __restrict__ o2){
    __shared__ float tin[2][18][304];
    int bl = blockIdx.x, s0 = blockIdx.y*16, which = blockIdx.z;
    const float* ca = which ? s2 : s1;
    const float* cf = which ? f2 : f1;
    float* od = which ? o2 : o1;
    float w[2][3][3];
    #pragma unroll
    for (int c = 0; c < 2; c++)
        #pragma unroll
        for (int dy = 0; dy < 3; dy++)
            #pragma unroll
            for (int dx = 0; dx < 3; dx++)
                w[c][dy][dx] = cw[c*9 + dy*3 + dx];
    float bias = cb[0];

    const int TOT = 2*18*304;
    for (int idx = threadIdx.x; idx < TOT; idx += 256){
        int c = idx / (18*304); int rem = idx - c*(18*304);
        int r = rem / 304; int le = rem - r*304;
        int gs = s0 + r - 1; int ge = le - 1;
        float v = 0.f;
        if (gs >= 0 && gs < SS && ge >= 0 && ge < EE){
            const float* src = c ? cf : ca;
            v = src[(size_t)bl*SS*EE + gs*EE + ge];
        }
        tin[c][r][le] = v;
    }
    __syncthreads();
    for (int idx = threadIdx.x; idx < 16*EE; idx += 256){
        int r = idx / EE; int e = idx - r*EE;
        float a = bias;
        #pragma unroll
        for (int c = 0; c < 2; c++)
            #pragma unroll
            for (int dy = 0; dy < 3; dy++)
                #pragma unroll
                for (int dx = 0; dx < 3; dx++)
                    a = fmaf(w[c][dy][dx], tin[c][r+dy][e+dx], a);
        od[(size_t)bl*SS*EE + (s0+r)*EE + e] = fast_tanh(a);
    }
}

// ---------------- mean over S -> res segment ----------------
// grid: (bc, 2), block 256
__global__ void mean_kernel(const float* __restrict__ x1, const float* __restrict__ x2,
                            float* __restrict__ res, int b0, int seg){
    int bl = blockIdx.x, which = blockIdx.y;
    const float* x = which ? x2 : x1;
    for (int e = threadIdx.x; e < EE; e += 256){
        float acc = 0.f;
        for (int s = 0; s < SS; s++) acc += x[(size_t)bl*SS*EE + s*EE + e];
        res[(size_t)(b0+bl)*FCIN + (which*3 + seg)*EE + e] = acc * (1.f/SS);
    }
}

// ---------------- attention pool (avg3) + residual update ----------------
// grid: (bc, 2, 2)  y = e-chunk, z = which
__global__ void pool_kernel(const float* __restrict__ o1, const float* __restrict__ o2,
                            const float* __restrict__ w1, const float* __restrict__ w2,
                            float* __restrict__ s1, float* __restrict__ s2){
    int bl = blockIdx.x;
    int e = blockIdx.y*256 + threadIdx.x;
    int which = blockIdx.z;
    if (e >= EE) return;
    const float* o = which ? o2 : o1;
    const float* w = which ? w2 : w1;
    float* sd = which ? s2 : s1;
    const float* ob = o + (size_t)bl*SS*EE;
    float* sb = sd + (size_t)bl*SS*EE;
    const float* wb = w + bl*SS;
    float qm = 0.f, q0 = ob[e] * wb[0], qp;
    for (int s = 0; s < SS; s++){
        qp = (s+1 < SS) ? ob[(s+1)*EE + e] * wb[s+1] : 0.f;
        sb[s*EE + e] += (qm + q0 + qp) * (1.f/3.f);
        qm = q0; q0 = qp;
    }
}

// ---------------- fc1: [512,1800] @ [1800,300]^T ----------------
// grid (8,5), block 256, 64x64 tile, kk=12
#define CKK 12
__global__ __launch_bounds__(256) void fc1_kernel(const float* __restrict__ res,
                                                  const float* __restrict__ fw,
                                                  const float* __restrict__ fb,
                                                  float* __restrict__ h){
    __shared__ float Xt[CKK][68];
    __shared__ float Wt[CKK][68];
    int bt = blockIdx.x, jt = blockIdx.y;
    int tid = threadIdx.x, tx = tid & 15, ty = tid >> 4;
    int b0l = bt*64, j0 = jt*64;
    float acc[4][4] = {};
    for (int k0 = 0; k0 < FCIN; k0 += CKK){
        #pragma unroll
        for (int u = 0; u < 3; u++){
            int idx = tid + u*256;     // < 768
            int a = idx / CKK, k = idx - a*CKK;
            Xt[k][a] = res[(size_t)(b0l+a)*FCIN + k0 + k];
            int gj = j0 + a;
            Wt[k][a] = (gj < HH) ? fw[(size_t)gj*FCIN + k0 + k] : 0.f;
        }
        __syncthreads();
        #pragma unroll
        for (int k = 0; k < CKK; k++){
            float xv[4], wv[4];
            #pragma unroll
            for (int r = 0; r < 4; r++) xv[r] = Xt[k][ty*4+r];
            #pragma unroll
            for (int c = 0; c < 4; c++) wv[c] = Wt[k][tx*4+c];
            #pragma unroll
            for (int r = 0; r < 4; r++)
                #pragma unroll
                for (int c = 0; c < 4; c++)
                    acc[r][c] = fmaf(xv[r], wv[c], acc[r][c]);
        }
        __syncthreads();
    }
    #pragma unroll
    for (int r = 0; r < 4; r++){
        int gb = b0l + ty*4 + r;
        #pragma unroll
        for (int c = 0; c < 4; c++){
            int gj = j0 + tx*4 + c;
            if (gj < HH) h[(size_t)gb*HH + gj] = acc[r][c] + fb[gj];
        }
    }
}

// ---------------- layernorm + relu + fc2 + softmax ----------------
// grid: B, block 256
__global__ void head_kernel(const float* __restrict__ h, const float* __restrict__ g,
                            const float* __restrict__ be, const float* __restrict__ f2w,
                            const float* __restrict__ f2b, float* __restrict__ out){
    int b = blockIdx.x, tid = threadIdx.x;
    __shared__ float arr[HH];
    __shared__ float s_s[4], s_q[4], r0[4], r1[4];
    float x0 = (tid < HH) ? h[(size_t)b*HH + tid] : 0.f;
    float x1 = (tid + 256 < HH) ? h[(size_t)b*HH + tid + 256] : 0.f;
    float s = x0 + x1, sq = x0*x0 + x1*x1;
    #pragma unroll
    for (int o = 32; o > 0; o >>= 1){ s += __shfl_down(s, o); sq += __shfl_down(sq, o); }
    int wv = tid >> 6, ln = tid & 63;
    if (ln == 0){ s_s[wv] = s; s_q[wv] = sq; }
    __syncthreads();
    s  = s_s[0] + s_s[1] + s_s[2] + s_s[3];
    sq = s_q[0] + s_q[1] + s_q[2] + s_q[3];
    float mean = s / HH;
    float var = sq / HH - mean*mean;
    float inv = rsqrtf(var + 1e-5f);
    if (tid < HH)       arr[tid]     = fmaxf((x0 - mean)*inv*g[tid]     + be[tid],     0.f);
    if (tid + 256 < HH) arr[tid+256] = fmaxf((x1 - mean)*inv*g[tid+256] + be[tid+256], 0.f);
    __syncthreads();
    float p0 = 0.f, p1 = 0.f;
    for (int j = tid; j < HH; j += 256){ float hv = arr[j]; p0 += hv*f2w[j]; p1 += hv*f2w[HH+j]; }
    #pragma unroll
    for (int o = 32; o > 0; o >>= 1){ p0 += __shfl_down(p0, o); p1 += __shfl_down(p1, o); }
    if (ln == 0){ r0[wv] = p0; r1[wv] = p1; }
    __syncthreads();
    if (tid == 0){
        float o0 = r0[0]+r0[1]+r0[2]+r0[3] + f2b[0];
        float o1 = r1[0]+r1[1]+r1[2]+r1[3] + f2b[1];
        out[b*2+0] = o0; out[b*2+1] = o1;
        float m = fmaxf(o0, o1);
        float e0 = __expf(o0 - m), e1 = __expf(o1 - m);
        float den = e0 + e1;
        out[BB*2 + b*2+0] = e0/den;
        out[BB*2 + b*2+1] = e1/den;
    }
}

extern "C" void kernel_launch(void* const* d_in, const int* in_sizes, int n_in,
                              void* d_out, int out_size, void* d_ws, size_t ws_size,
                              hipStream_t stream){
    const int*   seq1   = (const int*)d_in[0];
    const int*   seq2   = (const int*)d_in[1];
    const float* emb    = (const float*)d_in[2];
    const float* W      = (const float*)d_in[3];
    const float* conv_w = (const float*)d_in[4];
    const float* conv_b = (const float*)d_in[5];
    const float* fc1_w  = (const float*)d_in[6];
    const float* fc1_b  = (const float*)d_in[7];
    const float* ln_g   = (const float*)d_in[8];
    const float* ln_b   = (const float*)d_in[9];
    const float* fc2_w  = (const float*)d_in[10];
    const float* fc2_b  = (const float*)d_in[11];
    float* out = (float*)d_out;

    float* ws = (float*)d_ws;
    size_t fixedf = (size_t)BB*FCIN + (size_t)BB*HH;
    size_t perb   = (size_t)6*SS*EE + (size_t)SS*SS + 6*SS;
    size_t avail  = ws_size / 4;
    long long bcl = (long long)((avail > fixedf ? avail - fixedf : 0) / perb);
    int BC = (int)(bcl < 1 ? 1 : (bcl > BB ? BB : bcl));

    float* res = ws;
    float* hb  = res + (size_t)BB*FCIN;
    float* s1  = hb  + (size_t)BB*HH;
    float* s2  = s1  + (size_t)BC*SS*EE;
    float* f1b = s2  + (size_t)BC*SS*EE;
    float* f2b = f1b + (size_t)BC*SS*EE;
    float* o1  = f2b + (size_t)BC*SS*EE;
    float* o2  = o1  + (size_t)BC*SS*EE;
    float* Ab  = o2  + (size_t)BC*SS*EE;
    float* n1  = Ab  + (size_t)BC*SS*SS;
    float* n2  = n1 + (size_t)BC*SS;
    float* v1  = n2 + (size_t)BC*SS;
    float* v2  = v1 + (size_t)BC*SS;
    float* w1  = v2 + (size_t)BC*SS;
    float* w2  = w1 + (size_t)BC*SS;

    for (int b0 = 0; b0 < BB; b0 += BC){
        int bc = (BB - b0 < BC) ? (BB - b0) : BC;
        embed_kernel<<<dim3(bc*SS/4, 2), 256, 0, stream>>>(seq1, seq2, emb, s1, s2, v1, v2, b0);
        mean_kernel<<<dim3(bc, 2), 256, 0, stream>>>(s1, s2, res, b0, 0);
        for (int it = 0; it < LLI; it++){
            norm_kernel<<<dim3(bc*SS/4, 2), 256, 0, stream>>>(s1, s2, v1, v2, n1, n2);
            cross_kernel<0><<<bc, 256, 0, stream>>>(s1, s2, v1, v2, n1, n2, Ab, nullptr, nullptr);
            f_kernel<<<dim3(bc, 10, 2), 256, 0, stream>>>(Ab, W + (size_t)it*SS*EE, f1b, f2b);
            conv_kernel<<<dim3(bc, 8, 2), 256, 0, stream>>>(s1, s2, f1b, f2b,
                                                            conv_w + it*18, conv_b + it, o1, o2);
            mean_kernel<<<dim3(bc, 2), 256, 0, stream>>>(o1, o2, res, b0, it+1);
            norm_kernel<<<dim3(bc*SS/4, 2), 256, 0, stream>>>(o1, o2, v1, v2, n1, n2);
            cross_kernel<1><<<bc, 256, 0, stream>>>(o1, o2, v1, v2, n1, n2, nullptr, w1, w2);
            pool_kernel<<<dim3(bc, 2, 2), 256, 0, stream>>>(o1, o2, w1, w2, s1, s2);
        }
    }
    fc1_kernel<<<dim3(8, 5), 256, 0, stream>>>(res, fc1_w, fc1_b, hb);
    head_kernel<<<BB, 256, 0, stream>>>(hb, ln_g, ln_b, fc2_w, fc2_b, out);
}